// Round 9
// baseline (1489.051 us; speedup 1.0000x reference)
//
#include <hip/hip_runtime.h>

#define U_CNT 100000
#define I_CNT 50000
#define N_CNT 150000
#define NNZ_CNT 3200000
#define EMB 64

// Hybrid strategy:
//  - sign(y) discontinuity: y = spmm output computed in EXACT XLA-CPU f32
//    arithmetic (sequential ascending scatter-add of individually-rounded
//    products) -> bit-matches the reference's sign decisions at layer 1.
//  - everything continuous (gemv, BN stats, norm, noise) in f64: only needs
//    ~1e-9 accuracy (<< flip margins), so any parallel order / atomics are OK.
//  - en = f32(y + f32(f32(sign*noise_f32)*0.1f)) keeps ego within ~1 ulp of
//    XLA's f32 ego so layer-2/3 sign decisions stay on the right side.

__global__ void init_ego_kernel(const float* __restrict__ ue, const float* __restrict__ ie,
                                float* __restrict__ ego) {
  const int total = N_CNT * EMB, ucnt = U_CNT * EMB;
  for (int i = blockIdx.x * blockDim.x + threadIdx.x; i < total; i += gridDim.x * blockDim.x)
    ego[i] = (i < ucnt) ? ue[i] : ie[i - ucnt];
}

__global__ void build_row_ptr_kernel(const int* __restrict__ rows, int* __restrict__ rp) {
  int r = blockIdx.x * blockDim.x + threadIdx.x;
  if (r > N_CNT) return;
  int lo = 0, hi = NNZ_CNT;
  while (lo < hi) { int mid = (lo + hi) >> 1; if (rows[mid] < r) lo = mid + 1; else hi = mid; }
  rp[r] = lo;
}

__global__ void zero_stats_kernel(double* __restrict__ stats) {
  stats[threadIdx.x] = 0.0;  // 256 doubles
}

// EXACT XLA f32 scatter-add: acc = f32(acc + f32(v * x)), ascending edges.
__global__ __launch_bounds__(256) void spmm_kernel(const float* __restrict__ x, float* __restrict__ y,
                            const int* __restrict__ rp, const int* __restrict__ cols,
                            const float* __restrict__ vals) {
  const int wave = threadIdx.x >> 6, lane = threadIdx.x & 63;
  const int row = blockIdx.x * 4 + wave;
  if (row >= N_CNT) return;
  const int e0 = rp[row], e1 = rp[row + 1];
  float acc = 0.f;
  for (int e = e0; e < e1; ++e) {
    const int c = cols[e];
    acc = __fadd_rn(acc, __fmul_rn(vals[e], x[(size_t)c * EMB + lane]));
  }
  y[(size_t)row * EMB + lane] = acc;
}

// f64 gemv + leaky; writes h (f64) and accumulates per-column sum & sumsq (f64 atomics).
__global__ __launch_bounds__(256) void gemv_stats_kernel(const float* __restrict__ y, double* __restrict__ h,
                                  int nrows, const float* __restrict__ Wf, const float* __restrict__ bf,
                                  double* __restrict__ sum_out, double* __restrict__ sq_out) {
  __shared__ float ysh[4][EMB];
  __shared__ double red[4][EMB];
  const int wave = threadIdx.x >> 6, lane = threadIdx.x & 63;
  float w[EMB];
  #pragma unroll
  for (int k = 0; k < EMB; k += 4) {
    float4 t = *(const float4*)&Wf[lane * EMB + k];
    w[k] = t.x; w[k+1] = t.y; w[k+2] = t.z; w[k+3] = t.w;
  }
  const double bj = (double)bf[lane];
  double s = 0.0, q = 0.0;
  for (int r = blockIdx.x * 4 + wave; r < nrows; r += gridDim.x * 4) {
    ysh[wave][lane] = y[(size_t)r * EMB + lane];
    double acc = 0.0;
    #pragma unroll
    for (int k = 0; k < EMB; ++k) acc = fma((double)ysh[wave][k], (double)w[k], acc);
    double h0 = acc + bj;
    h0 = (h0 >= 0.0) ? h0 : 0.01 * h0;
    h[(size_t)r * EMB + lane] = h0;
    s += h0;
    q = fma(h0, h0, q);
  }
  red[wave][lane] = s;
  __syncthreads();
  if (wave == 0)
    atomicAdd(&sum_out[lane], red[0][lane] + red[1][lane] + red[2][lane] + red[3][lane]);
  __syncthreads();
  red[wave][lane] = q;
  __syncthreads();
  if (wave == 0)
    atomicAdd(&sq_out[lane], red[0][lane] + red[1][lane] + red[2][lane] + red[3][lane]);
}

// mu = S/n; var = Q/n - mu^2 (f64, clamped); R = 1/sqrt(var + 1e-5).
__global__ void finalize_stats_kernel(const double* __restrict__ stats, double* __restrict__ muR) {
  const int t = threadIdx.x;
  if (t >= 128) return;
  const int lane = t & 63;
  const bool isU = t < 64;
  const double* sp = stats + (isU ? 0 : 128);
  const double cnt = isU ? (double)U_CNT : (double)I_CNT;
  const double mu = sp[lane] / cnt;
  double var = sp[64 + lane] / cnt - mu * mu;
  if (var < 0.0) var = 0.0;
  muR[t] = mu;                       // mu: [0..63]=user, [64..127]=item
  muR[128 + t] = 1.0 / sqrt(var + 1e-5);  // R:  [128..191]=user, [192..255]=item
}

// hn = ((h-mu)*R)*g + bt (f64); nrm = sqrt(sum hn^2) f64 (shuffle, any order);
// noise = f32(hn/nrm); en = f32(y + f32(f32(sign*noise)*0.1f)).
__global__ __launch_bounds__(256) void apply_kernel(const float* __restrict__ y, const double* __restrict__ h,
                             float* __restrict__ ego, float* __restrict__ out_final,
                             float* __restrict__ out_cl, int nrows,
                             const double* __restrict__ mu_p, const double* __restrict__ R_p,
                             const float* __restrict__ g, const float* __restrict__ bt, int layer) {
  const int wave = threadIdx.x >> 6, lane = threadIdx.x & 63;
  const double muj = mu_p[lane], Rj = R_p[lane];
  const double gj = (double)g[lane], btj = (double)bt[lane];
  for (int r = blockIdx.x * 4 + wave; r < nrows; r += gridDim.x * 4) {
    const float yv = y[(size_t)r * EMB + lane];
    const double hv = h[(size_t)r * EMB + lane];
    const double hn = ((hv - muj) * Rj) * gj + btj;
    double ss = hn * hn;
    #pragma unroll
    for (int off = 32; off > 0; off >>= 1) ss += __shfl_xor(ss, off, 64);
    double nrm = sqrt(ss);
    if (nrm < 1e-12) nrm = 1e-12;
    const float noise = (float)(hn / nrm);
    const float sgn = (yv > 0.f) ? 1.f : ((yv < 0.f) ? -1.f : 0.f);
    const float t2 = __fmul_rn(__fmul_rn(sgn, noise), 0.1f);
    const float en = __fadd_rn(yv, t2);
    const int o = r * EMB + lane;
    ego[o] = en;
    if (layer == 0) { out_final[o] = en; out_cl[o] = en; }
    else if (layer == 1) { out_final[o] = __fadd_rn(out_final[o], en); }
    else { out_final[o] = __fdiv_rn(__fadd_rn(out_final[o], en), 3.0f); }
  }
}

extern "C" void kernel_launch(void* const* d_in, const int* in_sizes, int n_in,
                              void* d_out, int out_size, void* d_ws, size_t ws_size,
                              hipStream_t stream) {
  const float* user_emb = (const float*)d_in[0];
  const float* item_emb = (const float*)d_in[1];
  const int* adj_rows = (const int*)d_in[2];
  const int* adj_cols = (const int*)d_in[3];
  const float* adj_vals = (const float*)d_in[4];
  const float* Wu = (const float*)d_in[5];
  const float* bu = (const float*)d_in[6];
  const float* gu = (const float*)d_in[7];
  const float* btu = (const float*)d_in[8];
  const float* Wi = (const float*)d_in[9];
  const float* bi = (const float*)d_in[10];
  const float* gi = (const float*)d_in[11];
  const float* bti = (const float*)d_in[12];
  float* out = (float*)d_out;

  float* ego = (float*)d_ws;                            // [N,64] f32
  float* y = ego + (size_t)N_CNT * EMB;                 // [N,64] f32
  double* h = (double*)(y + (size_t)N_CNT * EMB);       // [N,64] f64
  double* stats = h + (size_t)N_CNT * EMB;              // 256 f64: Su,Qu,Si,Qi
  double* muR = stats + 256;                            // 256 f64: mu_u,mu_i,R_u,R_i
  int* rp = (int*)(muR + 256);                          // [N+1]

  float* out_final = out;                               // final [N,64] flat f32
  float* out_cl = out + (size_t)N_CNT * EMB;            // emb_cl [N,64] flat f32

  init_ego_kernel<<<2048, 256, 0, stream>>>(user_emb, item_emb, ego);
  build_row_ptr_kernel<<<(N_CNT + 1 + 255) / 256, 256, 0, stream>>>(adj_rows, rp);

  const size_t uoff = (size_t)U_CNT * EMB;
  for (int layer = 0; layer < 3; ++layer) {
    zero_stats_kernel<<<1, 256, 0, stream>>>(stats);
    spmm_kernel<<<(N_CNT + 3) / 4, 256, 0, stream>>>(ego, y, rp, adj_cols, adj_vals);
    gemv_stats_kernel<<<512, 256, 0, stream>>>(y, h, U_CNT, Wu, bu, stats, stats + 64);
    gemv_stats_kernel<<<256, 256, 0, stream>>>(y + uoff, h + uoff, I_CNT, Wi, bi,
                                               stats + 128, stats + 192);
    finalize_stats_kernel<<<1, 128, 0, stream>>>(stats, muR);
    apply_kernel<<<512, 256, 0, stream>>>(y, h, ego, out_final, out_cl, U_CNT,
                                          muR, muR + 128, gu, btu, layer);
    apply_kernel<<<256, 256, 0, stream>>>(y + uoff, h + uoff, ego + uoff, out_final + uoff,
                                          out_cl + uoff, I_CNT, muR + 64, muR + 192,
                                          gi, bti, layer);
  }
}

// Round 10
// 783.653 us; speedup vs baseline: 1.9001x; 1.9001x over previous
//
#include <hip/hip_runtime.h>

#define U_CNT 100000
#define I_CNT 50000
#define N_CNT 150000
#define NNZ_CNT 3200000
#define EMB 64

// Correctness recipe (locked in R9, do not perturb):
//  - spmm y: EXACT XLA-CPU f32 scatter-add order (ascending edges, per element
//    acc = f32(acc + f32(v*x))) -> sign(y) bit-matches the reference.
//  - gemv/BN-stats/norm/noise in f64 (order-free, atomics OK).
//  - en = f32(y + f32(f32(sign*noise_f32)*0.1f)).
// R10 perf changes (bit-identical math): 8-deep gather batching in spmm (MLP);
// U/I partitions merged into single launches for gemv_stats and apply.

__global__ void init_ego_kernel(const float* __restrict__ ue, const float* __restrict__ ie,
                                float* __restrict__ ego) {
  const int total = N_CNT * EMB, ucnt = U_CNT * EMB;
  for (int i = blockIdx.x * blockDim.x + threadIdx.x; i < total; i += gridDim.x * blockDim.x)
    ego[i] = (i < ucnt) ? ue[i] : ie[i - ucnt];
}

__global__ void build_row_ptr_kernel(const int* __restrict__ rows, int* __restrict__ rp) {
  int r = blockIdx.x * blockDim.x + threadIdx.x;
  if (r > N_CNT) return;
  int lo = 0, hi = NNZ_CNT;
  while (lo < hi) { int mid = (lo + hi) >> 1; if (rows[mid] < r) lo = mid + 1; else hi = mid; }
  rp[r] = lo;
}

__global__ void zero_stats_kernel(double* __restrict__ stats) {
  stats[threadIdx.x] = 0.0;  // 256 doubles
}

// EXACT XLA f32 scatter-add; loads batched 8-deep for MLP, adds strictly sequential.
__global__ __launch_bounds__(256) void spmm_kernel(const float* __restrict__ x, float* __restrict__ y,
                            const int* __restrict__ rp, const int* __restrict__ cols,
                            const float* __restrict__ vals) {
  const int wave = threadIdx.x >> 6, lane = threadIdx.x & 63;
  const int row = blockIdx.x * 4 + wave;
  if (row >= N_CNT) return;
  const int e0 = rp[row], e1 = rp[row + 1];
  float acc = 0.f;
  int e = e0;
  const int nmain = e0 + ((e1 - e0) & ~7);
  for (; e < nmain; e += 8) {
    float xv[8], vv[8];
    #pragma unroll
    for (int j = 0; j < 8; ++j) {
      const int c = cols[e + j];          // independent loads -> 8 outstanding
      vv[j] = vals[e + j];
      xv[j] = x[(size_t)c * EMB + lane];
    }
    #pragma unroll
    for (int j = 0; j < 8; ++j)           // sequential adds, original order
      acc = __fadd_rn(acc, __fmul_rn(vv[j], xv[j]));
  }
  for (; e < e1; ++e) {
    const int c = cols[e];
    acc = __fadd_rn(acc, __fmul_rn(vals[e], x[(size_t)c * EMB + lane]));
  }
  y[(size_t)row * EMB + lane] = acc;
}

// f64 gemv + leaky; writes h (f64), accumulates per-column sum & sumsq (f64 atomics).
// Merged U/I: blocks [0,GU) -> users, [GU,GU+GI) -> items.
#define GU 512
#define GI 256
__global__ __launch_bounds__(256) void gemv_stats_kernel(const float* __restrict__ y, double* __restrict__ h,
                                  const float* __restrict__ Wu, const float* __restrict__ bu,
                                  const float* __restrict__ Wi, const float* __restrict__ bi,
                                  double* __restrict__ stats) {
  __shared__ float ysh[4][EMB];
  __shared__ double red[4][EMB];
  const int wave = threadIdx.x >> 6, lane = threadIdx.x & 63;
  const bool isU = blockIdx.x < GU;
  const int blk = isU ? blockIdx.x : blockIdx.x - GU;
  const int nblk = isU ? GU : GI;
  const int nrows = isU ? U_CNT : I_CNT;
  const float* Wf = isU ? Wu : Wi;
  const float* bf = isU ? bu : bi;
  const float* yp = isU ? y : (y + (size_t)U_CNT * EMB);
  double* hp = isU ? h : (h + (size_t)U_CNT * EMB);
  double* sum_out = stats + (isU ? 0 : 128);
  double* sq_out = sum_out + 64;

  float w[EMB];
  #pragma unroll
  for (int k = 0; k < EMB; k += 4) {
    float4 t = *(const float4*)&Wf[lane * EMB + k];
    w[k] = t.x; w[k+1] = t.y; w[k+2] = t.z; w[k+3] = t.w;
  }
  const double bj = (double)bf[lane];
  double s = 0.0, q = 0.0;
  for (int r = blk * 4 + wave; r < nrows; r += nblk * 4) {
    ysh[wave][lane] = yp[(size_t)r * EMB + lane];
    double acc = 0.0;
    #pragma unroll
    for (int k = 0; k < EMB; ++k) acc = fma((double)ysh[wave][k], (double)w[k], acc);
    double h0 = acc + bj;
    h0 = (h0 >= 0.0) ? h0 : 0.01 * h0;
    hp[(size_t)r * EMB + lane] = h0;
    s += h0;
    q = fma(h0, h0, q);
  }
  red[wave][lane] = s;
  __syncthreads();
  if (wave == 0)
    atomicAdd(&sum_out[lane], red[0][lane] + red[1][lane] + red[2][lane] + red[3][lane]);
  __syncthreads();
  red[wave][lane] = q;
  __syncthreads();
  if (wave == 0)
    atomicAdd(&sq_out[lane], red[0][lane] + red[1][lane] + red[2][lane] + red[3][lane]);
}

// mu = S/n; var = Q/n - mu^2 (f64, clamped); R = 1/sqrt(var + 1e-5).
__global__ void finalize_stats_kernel(const double* __restrict__ stats, double* __restrict__ muR) {
  const int t = threadIdx.x;
  if (t >= 128) return;
  const int lane = t & 63;
  const bool isU = t < 64;
  const double* sp = stats + (isU ? 0 : 128);
  const double cnt = isU ? (double)U_CNT : (double)I_CNT;
  const double mu = sp[lane] / cnt;
  double var = sp[64 + lane] / cnt - mu * mu;
  if (var < 0.0) var = 0.0;
  muR[t] = mu;                            // [0..63]=mu_u, [64..127]=mu_i
  muR[128 + t] = 1.0 / sqrt(var + 1e-5);  // [128..191]=R_u, [192..255]=R_i
}

// hn = ((h-mu)*R)*g + bt (f64); nrm = sqrt(sum hn^2) f64 (shuffle);
// noise = f32(hn/nrm); en = f32(y + f32(f32(sign*noise)*0.1f)). Merged U/I.
__global__ __launch_bounds__(256) void apply_kernel(const float* __restrict__ y, const double* __restrict__ h,
                             float* __restrict__ ego, float* __restrict__ out_final,
                             float* __restrict__ out_cl,
                             const double* __restrict__ muR,
                             const float* __restrict__ gu, const float* __restrict__ btu,
                             const float* __restrict__ gi, const float* __restrict__ bti,
                             int layer) {
  const int wave = threadIdx.x >> 6, lane = threadIdx.x & 63;
  const bool isU = blockIdx.x < GU;
  const int blk = isU ? blockIdx.x : blockIdx.x - GU;
  const int nblk = isU ? GU : GI;
  const int nrows = isU ? U_CNT : I_CNT;
  const size_t off = isU ? 0 : (size_t)U_CNT * EMB;
  const double muj = muR[(isU ? 0 : 64) + lane];
  const double Rj = muR[128 + (isU ? 0 : 64) + lane];
  const double gj = (double)(isU ? gu[lane] : gi[lane]);
  const double btj = (double)(isU ? btu[lane] : bti[lane]);
  for (int r = blk * 4 + wave; r < nrows; r += nblk * 4) {
    const size_t o = off + (size_t)r * EMB + lane;
    const float yv = y[o];
    const double hv = h[o];
    const double hn = ((hv - muj) * Rj) * gj + btj;
    double ss = hn * hn;
    #pragma unroll
    for (int sh = 32; sh > 0; sh >>= 1) ss += __shfl_xor(ss, sh, 64);
    double nrm = sqrt(ss);
    if (nrm < 1e-12) nrm = 1e-12;
    const float noise = (float)(hn / nrm);
    const float sgn = (yv > 0.f) ? 1.f : ((yv < 0.f) ? -1.f : 0.f);
    const float t2 = __fmul_rn(__fmul_rn(sgn, noise), 0.1f);
    const float en = __fadd_rn(yv, t2);
    ego[o] = en;
    if (layer == 0) { out_final[o] = en; out_cl[o] = en; }
    else if (layer == 1) { out_final[o] = __fadd_rn(out_final[o], en); }
    else { out_final[o] = __fdiv_rn(__fadd_rn(out_final[o], en), 3.0f); }
  }
}

extern "C" void kernel_launch(void* const* d_in, const int* in_sizes, int n_in,
                              void* d_out, int out_size, void* d_ws, size_t ws_size,
                              hipStream_t stream) {
  const float* user_emb = (const float*)d_in[0];
  const float* item_emb = (const float*)d_in[1];
  const int* adj_rows = (const int*)d_in[2];
  const int* adj_cols = (const int*)d_in[3];
  const float* adj_vals = (const float*)d_in[4];
  const float* Wu = (const float*)d_in[5];
  const float* bu = (const float*)d_in[6];
  const float* gu = (const float*)d_in[7];
  const float* btu = (const float*)d_in[8];
  const float* Wi = (const float*)d_in[9];
  const float* bi = (const float*)d_in[10];
  const float* gi = (const float*)d_in[11];
  const float* bti = (const float*)d_in[12];
  float* out = (float*)d_out;

  float* ego = (float*)d_ws;                            // [N,64] f32
  float* y = ego + (size_t)N_CNT * EMB;                 // [N,64] f32
  double* h = (double*)(y + (size_t)N_CNT * EMB);       // [N,64] f64
  double* stats = h + (size_t)N_CNT * EMB;              // 256 f64: Su,Qu,Si,Qi
  double* muR = stats + 256;                            // 256 f64
  int* rp = (int*)(muR + 256);                          // [N+1]

  float* out_final = out;                               // final [N,64] flat f32
  float* out_cl = out + (size_t)N_CNT * EMB;            // emb_cl [N,64] flat f32

  init_ego_kernel<<<2048, 256, 0, stream>>>(user_emb, item_emb, ego);
  build_row_ptr_kernel<<<(N_CNT + 1 + 255) / 256, 256, 0, stream>>>(adj_rows, rp);

  for (int layer = 0; layer < 3; ++layer) {
    zero_stats_kernel<<<1, 256, 0, stream>>>(stats);
    spmm_kernel<<<(N_CNT + 3) / 4, 256, 0, stream>>>(ego, y, rp, adj_cols, adj_vals);
    gemv_stats_kernel<<<GU + GI, 256, 0, stream>>>(y, h, Wu, bu, Wi, bi, stats);
    finalize_stats_kernel<<<1, 128, 0, stream>>>(stats, muR);
    apply_kernel<<<GU + GI, 256, 0, stream>>>(y, h, ego, out_final, out_cl, muR,
                                              gu, btu, gi, bti, layer);
  }
}